// Round 4
// baseline (782.362 us; speedup 1.0000x reference)
//
#include <hip/hip_runtime.h>
#include <math.h>

// ---------------------------------------------------------------------------
// QuantBasicTransformerBlock on MI355X (gfx950). FP32 in/out, bf16 MFMA.
// B=4 N=1024 D=1024 H=16 DH=64 CTX_N=77 CTX_D=768 FF_HID=4096
//
// R4: attn rewritten LDS-free (direct-global MFMA frags, S^T pass A,
// swizzled per-wave Ps roundtrip, zero barriers); GEMMs use m97 recipe
// (global_load_lds width=16, unpadded [128][64] LDS).
//
// Workspace (80 MB):
//   W    0..16  bf16 transposed weights (JIT, reused per phase)
//   lnb 16..24  LN out bf16 [4096][1024]
//   qb  24..32  quant Q        | gg 24..56 bf16 [4096][4096] (FF phase)
//   kb  32..40  quant K        | cross: k2b 32..33, v2b 33..34,
//   vb  40..48  quant V        |        vbTc 34..35, ctxb 35..36
//   vbT 48..56  V^T [4][1024][1024] (self)
//   ao  56..64  attn out bf16
//   x1  64..80  fp32 trunk (x2 computed in place)
// ---------------------------------------------------------------------------

typedef unsigned short u16;
typedef __attribute__((ext_vector_type(8))) short short8;   // 8 bf16 = 4 VGPR
typedef __attribute__((ext_vector_type(4))) float f32x4;

__device__ inline float b2f(u16 v) { return __uint_as_float(((unsigned)v) << 16); }
__device__ inline u16 f2b(float f) {             // round-to-nearest-even
  unsigned u = __float_as_uint(f);
  unsigned r = u + 0x7fffu + ((u >> 16) & 1u);
  return (u16)(r >> 16);
}

// async global->LDS, 16 B per lane (emits global_load_lds_dwordx4)
__device__ inline void glds16(const u16* g, u16* l) {
  __builtin_amdgcn_global_load_lds(
      (const __attribute__((address_space(1))) void*)g,
      (__attribute__((address_space(3))) void*)l, 16, 0, 0);
}

// ---------------------------------------------------------------------------
// Transpose fp32 in[R][C] -> bf16 out[C][R].  R,C multiples of 32.
// ---------------------------------------------------------------------------
__global__ __launch_bounds__(256) void transpose_k(const float* __restrict__ in,
                                                   u16* __restrict__ out,
                                                   int R, int C) {
  __shared__ float t[32][33];
  int tx = threadIdx.x & 31, ty = threadIdx.x >> 5;  // 32 x 8
  int c0 = blockIdx.x * 32, r0 = blockIdx.y * 32;
#pragma unroll
  for (int i = 0; i < 32; i += 8)
    t[ty + i][tx] = in[(size_t)(r0 + ty + i) * C + c0 + tx];
  __syncthreads();
#pragma unroll
  for (int i = 0; i < 32; i += 8)
    out[(size_t)(c0 + ty + i) * R + r0 + tx] = f2b(t[tx][ty + i]);
}

// ---------------------------------------------------------------------------
// Batched u16 transpose: in[b][n][C=1024] -> out[b][c][NKP], n < NK (clamped).
// grid (ceil(NK/32), 32, B)
// ---------------------------------------------------------------------------
__global__ __launch_bounds__(256) void tr16_k(const u16* __restrict__ in,
                                              u16* __restrict__ out, int NK,
                                              int NKP) {
  __shared__ u16 t[32][33];
  int tx = threadIdx.x & 31, ty = threadIdx.x >> 5;
  int n0 = blockIdx.x * 32, c0 = blockIdx.y * 32, b = blockIdx.z;
  const u16* ib = in + (size_t)b * NK * 1024;
  u16* ob = out + (size_t)b * 1024 * NKP;
#pragma unroll
  for (int i = 0; i < 32; i += 8) {
    int n = n0 + ty + i;
    n = n < NK ? n : NK - 1;
    t[ty + i][tx] = ib[(size_t)n * 1024 + c0 + tx];
  }
  __syncthreads();
#pragma unroll
  for (int i = 0; i < 32; i += 8)
    ob[(size_t)(c0 + ty + i) * NKP + n0 + tx] = t[tx][ty + i];
}

// ---------------------------------------------------------------------------
// fp32 -> bf16 cast, 4 elem/thread (n divisible by 1024).
// ---------------------------------------------------------------------------
__global__ __launch_bounds__(256) void cast_k(const float* __restrict__ in,
                                              u16* __restrict__ out) {
  int i = (blockIdx.x * 256 + threadIdx.x) * 4;
  float4 v = *(const float4*)(in + i);
  out[i + 0] = f2b(v.x);
  out[i + 1] = f2b(v.y);
  out[i + 2] = f2b(v.z);
  out[i + 3] = f2b(v.w);
}

// ---------------------------------------------------------------------------
// LayerNorm over D=1024 (fp32 in, bf16 out). One block per row.
// ---------------------------------------------------------------------------
__global__ __launch_bounds__(256) void ln_k(const float* __restrict__ X,
                                            const float* __restrict__ W,
                                            const float* __restrict__ Bi,
                                            u16* __restrict__ Out) {
  const int row = blockIdx.x, tid = threadIdx.x;
  float4 x = *(const float4*)(X + (size_t)row * 1024 + tid * 4);
  float s = x.x + x.y + x.z + x.w;
  float s2 = x.x * x.x + x.y * x.y + x.z * x.z + x.w * x.w;
#pragma unroll
  for (int off = 32; off >= 1; off >>= 1) {
    s += __shfl_down(s, off);
    s2 += __shfl_down(s2, off);
  }
  __shared__ float red[8];
  int wave = tid >> 6, lane = tid & 63;
  if (lane == 0) { red[wave] = s; red[4 + wave] = s2; }
  __syncthreads();
  s = red[0] + red[1] + red[2] + red[3];
  s2 = red[4] + red[5] + red[6] + red[7];
  float mean = s * 0.0009765625f;
  float var = s2 * 0.0009765625f - mean * mean;
  float rs = rsqrtf(var + 1e-5f);
  float4 w = *(const float4*)(W + tid * 4);
  float4 b = *(const float4*)(Bi + tid * 4);
  u16* orow = Out + (size_t)row * 1024 + tid * 4;
  orow[0] = f2b((x.x - mean) * rs * w.x + b.x);
  orow[1] = f2b((x.y - mean) * rs * w.y + b.y);
  orow[2] = f2b((x.z - mean) * rs * w.z + b.z);
  orow[3] = f2b((x.w - mean) * rs * w.w + b.w);
}

// ---------------------------------------------------------------------------
// GEMM (m97 recipe): C[M,N] = A[M,K] @ Bt[N,K], bf16, 128x128 tile, BK=64,
// unpadded LDS + global_load_lds dwordx4 staging.
// EPI: 0 = fake-quant -> int-in-bf16;  1 = +bias +fp32 residual -> fp32
// ---------------------------------------------------------------------------
template <int EPI>
__global__ __launch_bounds__(256, 2) void gemm_bt(
    const u16* __restrict__ A, int lda, const u16* __restrict__ Bt, int ldb,
    void* __restrict__ Cp, int ldc, const float* __restrict__ bias,
    const float* __restrict__ res, int ldr, const float* __restrict__ dp,
    int M, int N, int K) {
  __shared__ __align__(16) u16 As[128 * 64];
  __shared__ __align__(16) u16 Bs[128 * 64];
  const int tid = threadIdx.x;
  const int lane = tid & 63, wave = tid >> 6;
  const int qd = lane >> 4, cl = lane & 15;
  const int wm = (wave & 1) << 6, wn = (wave >> 1) << 6;
  const int m0 = blockIdx.x * 128, n0 = blockIdx.y * 128;

  f32x4 acc[4][4];
  const f32x4 zero = {0.f, 0.f, 0.f, 0.f};
#pragma unroll
  for (int i = 0; i < 4; i++)
#pragma unroll
    for (int j = 0; j < 4; j++) acc[i][j] = zero;

  for (int k0 = 0; k0 < K; k0 += 64) {
    __syncthreads();
#pragma unroll
    for (int it = 0; it < 4; ++it) {
      int ch = it * 256 + tid;           // 0..1023 chunks of 8 u16
      int r = ch >> 3, cc = (ch & 7) << 3;
      int gr = m0 + r;
      gr = gr < M ? gr : M - 1;          // clamp reads; stores guarded below
      glds16(A + (size_t)gr * lda + k0 + cc, As + ch * 8);
      glds16(Bt + (size_t)(n0 + r) * ldb + k0 + cc, Bs + ch * 8);
    }
    __syncthreads();
#pragma unroll
    for (int ks = 0; ks < 64; ks += 32) {
      short8 af[4], bf[4];
#pragma unroll
      for (int t = 0; t < 4; t++)
        af[t] = *(const short8*)(As + (wm + t * 16 + cl) * 64 + ks + qd * 8);
#pragma unroll
      for (int t = 0; t < 4; t++)
        bf[t] = *(const short8*)(Bs + (wn + t * 16 + cl) * 64 + ks + qd * 8);
#pragma unroll
      for (int mt = 0; mt < 4; mt++)
#pragma unroll
        for (int nt = 0; nt < 4; nt++)
          acc[mt][nt] = __builtin_amdgcn_mfma_f32_16x16x32_bf16(
              af[mt], bf[nt], acc[mt][nt], 0, 0, 0);
    }
  }

  float dscale = 1.f;
  if constexpr (EPI == 0) dscale = 1.0f / dp[0];
#pragma unroll
  for (int mt = 0; mt < 4; ++mt) {
#pragma unroll
    for (int r = 0; r < 4; ++r) {
      int row = m0 + wm + mt * 16 + qd * 4 + r;
      if (row >= M) continue;
#pragma unroll
      for (int nt = 0; nt < 4; ++nt) {
        int col = n0 + wn + nt * 16 + cl;
        float v = acc[mt][nt][r];
        if constexpr (EPI == 0) {
          float xq = rintf(v * dscale) + 128.f;
          xq = fminf(fmaxf(xq, 0.f), 255.f);
          ((u16*)Cp)[(size_t)row * ldc + col] = f2b(xq - 128.f);
        } else {
          v += bias[col] + res[(size_t)row * ldr + col];
          ((float*)Cp)[(size_t)row * ldc + col] = v;
        }
      }
    }
  }
}

// ---------------------------------------------------------------------------
// Fused FF1 + GEGLU (m97 staging): gg = (A@W1a + b1a) * gelu(A@W1g + b1g)
// ---------------------------------------------------------------------------
__global__ __launch_bounds__(256, 2) void ff1_geglu_k(
    const u16* __restrict__ A, const u16* __restrict__ W1t,
    const float* __restrict__ b1, u16* __restrict__ gg, int M) {
  __shared__ __align__(16) u16 As[128 * 64];
  __shared__ __align__(16) u16 Ba[64 * 64];
  __shared__ __align__(16) u16 Bg[64 * 64];
  const int tid = threadIdx.x;
  const int lane = tid & 63, wave = tid >> 6;
  const int qd = lane >> 4, cl = lane & 15;
  const int wm = (wave & 1) << 6, wn = (wave >> 1) << 5;
  const int m0 = blockIdx.x * 128, n0 = blockIdx.y * 64;

  f32x4 aca[4][2], acg[4][2];
  const f32x4 zero = {0.f, 0.f, 0.f, 0.f};
#pragma unroll
  for (int i = 0; i < 4; i++)
#pragma unroll
    for (int j = 0; j < 2; j++) { aca[i][j] = zero; acg[i][j] = zero; }

  for (int k0 = 0; k0 < 1024; k0 += 64) {
    __syncthreads();
#pragma unroll
    for (int it = 0; it < 4; ++it) {
      int ch = it * 256 + tid;
      int r = ch >> 3, cc = (ch & 7) << 3;
      glds16(A + (size_t)(m0 + r) * 1024 + k0 + cc, As + ch * 8);
    }
#pragma unroll
    for (int it = 0; it < 2; ++it) {
      int ch = it * 256 + tid;          // 0..511
      int r = ch >> 3, cc = (ch & 7) << 3;
      glds16(W1t + (size_t)(n0 + r) * 1024 + k0 + cc, Ba + ch * 8);
      glds16(W1t + (size_t)(4096 + n0 + r) * 1024 + k0 + cc, Bg + ch * 8);
    }
    __syncthreads();
#pragma unroll
    for (int ks = 0; ks < 64; ks += 32) {
      short8 af[4], ba[2], bg[2];
#pragma unroll
      for (int t = 0; t < 4; t++)
        af[t] = *(const short8*)(As + (wm + t * 16 + cl) * 64 + ks + qd * 8);
#pragma unroll
      for (int t = 0; t < 2; t++) {
        ba[t] = *(const short8*)(Ba + (wn + t * 16 + cl) * 64 + ks + qd * 8);
        bg[t] = *(const short8*)(Bg + (wn + t * 16 + cl) * 64 + ks + qd * 8);
      }
#pragma unroll
      for (int mt = 0; mt < 4; mt++)
#pragma unroll
        for (int nt = 0; nt < 2; nt++) {
          aca[mt][nt] = __builtin_amdgcn_mfma_f32_16x16x32_bf16(
              af[mt], ba[nt], aca[mt][nt], 0, 0, 0);
          acg[mt][nt] = __builtin_amdgcn_mfma_f32_16x16x32_bf16(
              af[mt], bg[nt], acg[mt][nt], 0, 0, 0);
        }
    }
  }
#pragma unroll
  for (int mt = 0; mt < 4; ++mt)
#pragma unroll
    for (int r = 0; r < 4; ++r) {
      int row = m0 + wm + mt * 16 + qd * 4 + r;
#pragma unroll
      for (int nt = 0; nt < 2; ++nt) {
        int col = n0 + wn + nt * 16 + cl;
        float a = aca[mt][nt][r] + b1[col];
        float g = acg[mt][nt][r] + b1[4096 + col];
        float ge = 0.5f * g * (1.0f + erff(g * 0.70710678118654752f));
        gg[(size_t)row * 4096 + col] = f2b(a * ge);
      }
    }
}

// ---------------------------------------------------------------------------
// Two-pass quantized attention, LDS-free fragments. Q/K ints in bf16 (exact).
// Block = 64 q-rows of one (b,h); wave = 16 rows; zero __syncthreads.
// Pass A computes S^T = K.Q^T (lane owns ONE q-row -> 4 shfls/tile).
// Pass B computes S = Q.K^T, quantizes P, per-wave swizzled Ps roundtrip
// (conflict-free), PV with V^T fragments read directly from vbT.
// ---------------------------------------------------------------------------
__global__ __launch_bounds__(256, 4) void attn_k(
    const u16* __restrict__ Q, const u16* __restrict__ Kb,
    const u16* __restrict__ VbT, u16* __restrict__ O,
    const float* dqp, const float* dkp, const float* dvp, const float* dwp,
    int NK, int NKP) {
  __shared__ __align__(16) u16 Ps[4][16][72];   // per-wave quantized P
  const int tid = threadIdx.x;
  const int lane = tid & 63, wave = tid >> 6;
  const int qd = lane >> 4, cl = lane & 15;
  const int b = blockIdx.z, h = blockIdx.y, qt = blockIdx.x;
  const float sscale = dqp[0] * dkp[0] * 0.125f;  // dq*dk*DH^-0.5
  const float oscale = dwp[0] * dvp[0];
  const float inv_dw = 1.0f / dwp[0];
  const f32x4 zero = {0.f, 0.f, 0.f, 0.f};

  // Q fragment for rows q = wave*16 + cl (A-frag of Q == B-frag of Q^T)
  const u16* qrow = Q + (size_t)(b * 1024 + qt * 64 + wave * 16 + cl) * 1024 + h * 64;
  short8 qf[2];
  qf[0] = *(const short8*)(qrow + qd * 8);
  qf[1] = *(const short8*)(qrow + 32 + qd * 8);

  const u16* kbase = Kb + (size_t)(b * NK) * 1024 + h * 64;
  const u16* vbase = VbT + ((size_t)b * 1024 + h * 64) * NKP;

  // -------- PASS A: S^T tiles; lane owns q-row cl --------
  float m_s = -1e30f, l_s = 0.f;
  for (int j0 = 0; j0 < NK; j0 += 64) {
    const bool full = (j0 + 64 <= NK);
    float sc[16];
#pragma unroll
    for (int nt = 0; nt < 4; ++nt) {
      const u16* krow = kbase + (size_t)(j0 + nt * 16 + cl) * 1024;
      short8 kf0 = *(const short8*)(krow + qd * 8);
      short8 kf1 = *(const short8*)(krow + 32 + qd * 8);
      f32x4 st = zero;
      st = __builtin_amdgcn_mfma_f32_16x16x32_bf16(kf0, qf[0], st, 0, 0, 0);
      st = __builtin_amdgcn_mfma_f32_16x16x32_bf16(kf1, qf[1], st, 0, 0, 0);
#pragma unroll
      for (int r = 0; r < 4; ++r) {
        int key = j0 + nt * 16 + qd * 4 + r;
        sc[nt * 4 + r] = (full || key < NK) ? st[r] * sscale : -1e30f;
      }
    }
    float mx = sc[0];
#pragma unroll
    for (int i = 1; i < 16; ++i) mx = fmaxf(mx, sc[i]);
    mx = fmaxf(mx, __shfl_xor(mx, 16));
    mx = fmaxf(mx, __shfl_xor(mx, 32));
    float mn = fmaxf(m_s, mx);
    float ss = 0.f;
#pragma unroll
    for (int i = 0; i < 16; ++i) ss += __expf(sc[i] - mn);
    ss += __shfl_xor(ss, 16);
    ss += __shfl_xor(ss, 32);
    l_s = l_s * __expf(m_s - mn) + ss;
    m_s = mn;
  }
  // redistribute row stats to D-layout rows (qd*4+r)
  float il_s = 1.0f / l_s;
  float m_row[4], il_row[4];
#pragma unroll
  for (int r = 0; r < 4; ++r) {
    m_row[r] = __shfl(m_s, qd * 4 + r);
    il_row[r] = __shfl(il_s, qd * 4 + r);
  }

  // -------- PASS B: S tiles, quantize P, PV --------
  f32x4 oacc[4];
#pragma unroll
  for (int t = 0; t < 4; t++) oacc[t] = zero;
  const int swz = ((cl >> 2) & 3) << 3;

  for (int j0 = 0; j0 < NK; j0 += 64) {
    const bool full = (j0 + 64 <= NK);
#pragma unroll
    for (int nt = 0; nt < 4; ++nt) {
      const u16* krow = kbase + (size_t)(j0 + nt * 16 + cl) * 1024;
      short8 kf0 = *(const short8*)(krow + qd * 8);
      short8 kf1 = *(const short8*)(krow + 32 + qd * 8);
      f32x4 s = zero;
      s = __builtin_amdgcn_mfma_f32_16x16x32_bf16(qf[0], kf0, s, 0, 0, 0);
      s = __builtin_amdgcn_mfma_f32_16x16x32_bf16(qf[1], kf1, s, 0, 0, 0);
      int key = j0 + nt * 16 + cl;
      bool kv = full || key < NK;
#pragma unroll
      for (int r = 0; r < 4; ++r) {
        float aw = 0.f;
        if (kv) {
          float attn = __expf(s[r] * sscale - m_row[r]) * il_row[r];
          aw = fminf(fmaxf(rintf(attn * inv_dw), 0.f), 255.f);
        }
        int row = qd * 4 + r;
        // bank-swizzle: col ^ (qd<<3) -> all 32 banks, conflict-free
        Ps[wave][row][(nt * 16 + cl) ^ (qd << 3)] = f2b(aw);
      }
    }
    // per-wave LDS ordering: DS ops execute in program order, no barrier
#pragma unroll
    for (int ks = 0; ks < 2; ++ks) {
      short8 pf = *(const short8*)(&Ps[wave][cl][(ks * 32 + qd * 8) ^ swz]);
#pragma unroll
      for (int dt = 0; dt < 4; ++dt) {
        short8 vf = *(const short8*)(vbase + (size_t)(dt * 16 + cl) * NKP +
                                     j0 + ks * 32 + qd * 8);
        oacc[dt] =
            __builtin_amdgcn_mfma_f32_16x16x32_bf16(pf, vf, oacc[dt], 0, 0, 0);
      }
    }
  }
#pragma unroll
  for (int dt = 0; dt < 4; ++dt)
#pragma unroll
    for (int r = 0; r < 4; r++) {
      size_t addr =
          (size_t)(b * 1024 + qt * 64 + wave * 16 + qd * 4 + r) * 1024 +
          h * 64 + dt * 16 + cl;
      O[addr] = f2b(oacc[dt][r] * oscale);
    }
}

// ---------------------------------------------------------------------------
extern "C" void kernel_launch(void* const* d_in, const int* in_sizes, int n_in,
                              void* d_out, int out_size, void* d_ws,
                              size_t ws_size, hipStream_t stream) {
  (void)in_sizes; (void)n_in; (void)out_size; (void)ws_size;
  const float* x    = (const float*)d_in[0];
  const float* ctx  = (const float*)d_in[1];
  const float* n1w  = (const float*)d_in[2];
  const float* n1b  = (const float*)d_in[3];
  const float* n2w  = (const float*)d_in[4];
  const float* n2b  = (const float*)d_in[5];
  const float* n3w  = (const float*)d_in[6];
  const float* n3b  = (const float*)d_in[7];
  const float* a1wq = (const float*)d_in[8];
  const float* a1wk = (const float*)d_in[9];
  const float* a1wv = (const float*)d_in[10];
  const float* a1wo = (const float*)d_in[11];
  const float* a1bo = (const float*)d_in[12];
  const float* a2wq = (const float*)d_in[13];
  const float* a2wk = (const float*)d_in[14];
  const float* a2wv = (const float*)d_in[15];
  const float* a2wo = (const float*)d_in[16];
  const float* a2bo = (const float*)d_in[17];
  const float* ffw1 = (const float*)d_in[18];
  const float* ffb1 = (const float*)d_in[19];
  const float* ffw2 = (const float*)d_in[20];
  const float* ffb2 = (const float*)d_in[21];
  const float* d1q = (const float*)d_in[22];
  const float* d1k = (const float*)d_in[23];
  const float* d1v = (const float*)d_in[24];
  const float* d1w = (const float*)d_in[25];
  const float* d2q = (const float*)d_in[26];
  const float* d2k = (const float*)d_in[27];
  const float* d2v = (const float*)d_in[28];
  const float* d2w = (const float*)d_in[29];

  char* ws = (char*)d_ws;
  const size_t MB = 1u << 20;
  u16* W    = (u16*)(ws + 0 * MB);
  u16* lnb  = (u16*)(ws + 16 * MB);
  u16* qb   = (u16*)(ws + 24 * MB);
  u16* kb   = (u16*)(ws + 32 * MB);
  u16* vb   = (u16*)(ws + 40 * MB);
  u16* vbT  = (u16*)(ws + 48 * MB);   // [4][1024][1024]
  u16* ao   = (u16*)(ws + 56 * MB);
  float* x1 = (float*)(ws + 64 * MB); // fp32 trunk (x2 in place) -> 80 MB
  u16* k2b  = (u16*)(ws + 32 * MB);   // cross (kb/vb dead)
  u16* v2b  = (u16*)(ws + 33 * MB);
  u16* vbTc = (u16*)(ws + 34 * MB);   // [4][1024][128]
  u16* ctxb = (u16*)(ws + 35 * MB);   // [308][768]
  u16* gg   = (u16*)(ws + 24 * MB);   // FF: [4096][4096] over qb..vbT -> 56 MB

  u16* WT0 = W;
  u16* WT1 = (u16*)(ws + 2 * MB);
  u16* WT2 = (u16*)(ws + 4 * MB);
  u16* WT3 = (u16*)(ws + 6 * MB);

  dim3 T256(256);
  // ================= attn1 (self) =================
  transpose_k<<<dim3(32, 32), T256, 0, stream>>>(a1wq, WT0, 1024, 1024);
  transpose_k<<<dim3(32, 32), T256, 0, stream>>>(a1wk, WT1, 1024, 1024);
  transpose_k<<<dim3(32, 32), T256, 0, stream>>>(a1wv, WT2, 1024, 1024);
  transpose_k<<<dim3(32, 32), T256, 0, stream>>>(a1wo, WT3, 1024, 1024);
  ln_k<<<4096, T256, 0, stream>>>(x, n1w, n1b, lnb);
  gemm_bt<0><<<dim3(32, 8), T256, 0, stream>>>(lnb, 1024, WT0, 1024, qb, 1024,
                                               nullptr, nullptr, 0, d1q, 4096,
                                               1024, 1024);
  gemm_bt<0><<<dim3(32, 8), T256, 0, stream>>>(lnb, 1024, WT1, 1024, kb, 1024,
                                               nullptr, nullptr, 0, d1k, 4096,
                                               1024, 1024);
  gemm_bt<0><<<dim3(32, 8), T256, 0, stream>>>(lnb, 1024, WT2, 1024, vb, 1024,
                                               nullptr, nullptr, 0, d1v, 4096,
                                               1024, 1024);
  tr16_k<<<dim3(32, 32, 4), T256, 0, stream>>>(vb, vbT, 1024, 1024);
  attn_k<<<dim3(16, 16, 4), T256, 0, stream>>>(qb, kb, vbT, ao, d1q, d1k, d1v,
                                               d1w, 1024, 1024);
  gemm_bt<1><<<dim3(32, 8), T256, 0, stream>>>(ao, 1024, WT3, 1024, x1, 1024,
                                               a1bo, x, 1024, nullptr, 4096,
                                               1024, 1024);
  // ================= attn2 (cross, CTX_N=77) =================
  transpose_k<<<dim3(32, 32), T256, 0, stream>>>(a2wq, WT0, 1024, 1024);
  transpose_k<<<dim3(32, 32), T256, 0, stream>>>(a2wo, WT1, 1024, 1024);
  transpose_k<<<dim3(32, 24), T256, 0, stream>>>(a2wk, WT2, 768, 1024);
  transpose_k<<<dim3(32, 24), T256, 0, stream>>>(a2wv, WT3, 768, 1024);
  ln_k<<<4096, T256, 0, stream>>>(x1, n2w, n2b, lnb);
  cast_k<<<231, T256, 0, stream>>>(ctx, ctxb);  // 308*768 = 231*1024
  gemm_bt<0><<<dim3(32, 8), T256, 0, stream>>>(lnb, 1024, WT0, 1024, qb, 1024,
                                               nullptr, nullptr, 0, d2q, 4096,
                                               1024, 1024);
  gemm_bt<0><<<dim3(3, 8), T256, 0, stream>>>(ctxb, 768, WT2, 768, k2b, 1024,
                                              nullptr, nullptr, 0, d2k, 308,
                                              1024, 768);
  gemm_bt<0><<<dim3(3, 8), T256, 0, stream>>>(ctxb, 768, WT3, 768, v2b, 1024,
                                              nullptr, nullptr, 0, d2v, 308,
                                              1024, 768);
  tr16_k<<<dim3(3, 32, 4), T256, 0, stream>>>(v2b, vbTc, 77, 128);
  attn_k<<<dim3(16, 16, 4), T256, 0, stream>>>(qb, k2b, vbTc, ao, d2q, d2k,
                                               d2v, d2w, 77, 128);
  gemm_bt<1><<<dim3(32, 8), T256, 0, stream>>>(ao, 1024, WT1, 1024, x1, 1024,
                                               a2bo, x1, 1024, nullptr, 4096,
                                               1024, 1024);  // x2 in place
  // ================= GEGLU FF =================
  transpose_k<<<dim3(256, 32), T256, 0, stream>>>(ffw1, W, 1024, 8192);
  ln_k<<<4096, T256, 0, stream>>>(x1, n3w, n3b, lnb);
  ff1_geglu_k<<<dim3(32, 64), T256, 0, stream>>>(lnb, W, ffb1, gg, 4096);
  transpose_k<<<dim3(32, 128), T256, 0, stream>>>(ffw2, W, 4096, 1024);
  gemm_bt<1><<<dim3(32, 8), T256, 0, stream>>>(gg, 4096, W, 4096, d_out, 1024,
                                               ffb2, x1, 1024, nullptr, 4096,
                                               1024, 4096);
}

// Round 5
// 673.037 us; speedup vs baseline: 1.1624x; 1.1624x over previous
//
#include <hip/hip_runtime.h>
#include <math.h>

// ---------------------------------------------------------------------------
// QuantBasicTransformerBlock on MI355X (gfx950). FP32 in/out, bf16 MFMA.
// B=4 N=1024 D=1024 H=16 DH=64 CTX_N=77 CTX_D=768 FF_HID=4096
//
// R5: attention = LDS-staged K/V^T tiles (coalesced glds16), S^T form in both
// passes (lane owns q-row cl: 2 shfl-pairs/tile in pass A, zero in pass B),
// packed b64 Ps writes, pre-transposed V. GEMMs keep the m97 recipe.
// ---------------------------------------------------------------------------

typedef unsigned short u16;
typedef __attribute__((ext_vector_type(8))) short short8;   // 8 bf16 = 4 VGPR
typedef __attribute__((ext_vector_type(4))) float f32x4;

__device__ inline float b2f(u16 v) { return __uint_as_float(((unsigned)v) << 16); }
__device__ inline u16 f2b(float f) {             // round-to-nearest-even
  unsigned u = __float_as_uint(f);
  unsigned r = u + 0x7fffu + ((u >> 16) & 1u);
  return (u16)(r >> 16);
}

// async global->LDS, 16 B per lane (emits global_load_lds_dwordx4)
__device__ inline void glds16(const u16* g, u16* l) {
  __builtin_amdgcn_global_load_lds(
      (const __attribute__((address_space(1))) void*)g,
      (__attribute__((address_space(3))) void*)l, 16, 0, 0);
}

// ---------------------------------------------------------------------------
// Transpose fp32 in[R][C] -> bf16 out[C][R].  R,C multiples of 32.
// ---------------------------------------------------------------------------
__global__ __launch_bounds__(256) void transpose_k(const float* __restrict__ in,
                                                   u16* __restrict__ out,
                                                   int R, int C) {
  __shared__ float t[32][33];
  int tx = threadIdx.x & 31, ty = threadIdx.x >> 5;  // 32 x 8
  int c0 = blockIdx.x * 32, r0 = blockIdx.y * 32;
#pragma unroll
  for (int i = 0; i < 32; i += 8)
    t[ty + i][tx] = in[(size_t)(r0 + ty + i) * C + c0 + tx];
  __syncthreads();
#pragma unroll
  for (int i = 0; i < 32; i += 8)
    out[(size_t)(c0 + ty + i) * R + r0 + tx] = f2b(t[tx][ty + i]);
}

// ---------------------------------------------------------------------------
// Batched u16 transpose: in[b][n][1024] -> out[b][c][NKP], n clamped to NK.
// grid (ceil(NK/32), 32, B)
// ---------------------------------------------------------------------------
__global__ __launch_bounds__(256) void tr16_k(const u16* __restrict__ in,
                                              u16* __restrict__ out, int NK,
                                              int NKP) {
  __shared__ u16 t[32][33];
  int tx = threadIdx.x & 31, ty = threadIdx.x >> 5;
  int n0 = blockIdx.x * 32, c0 = blockIdx.y * 32, b = blockIdx.z;
  const u16* ib = in + (size_t)b * NK * 1024;
  u16* ob = out + (size_t)b * 1024 * NKP;
#pragma unroll
  for (int i = 0; i < 32; i += 8) {
    int n = n0 + ty + i;
    n = n < NK ? n : NK - 1;
    t[ty + i][tx] = ib[(size_t)n * 1024 + c0 + tx];
  }
  __syncthreads();
#pragma unroll
  for (int i = 0; i < 32; i += 8)
    ob[(size_t)(c0 + ty + i) * NKP + n0 + tx] = t[tx][ty + i];
}

// ---------------------------------------------------------------------------
// fp32 -> bf16 cast, 4 elem/thread (n divisible by 1024).
// ---------------------------------------------------------------------------
__global__ __launch_bounds__(256) void cast_k(const float* __restrict__ in,
                                              u16* __restrict__ out) {
  int i = (blockIdx.x * 256 + threadIdx.x) * 4;
  float4 v = *(const float4*)(in + i);
  out[i + 0] = f2b(v.x);
  out[i + 1] = f2b(v.y);
  out[i + 2] = f2b(v.z);
  out[i + 3] = f2b(v.w);
}

// ---------------------------------------------------------------------------
// LayerNorm over D=1024 (fp32 in, bf16 out). One block per row.
// ---------------------------------------------------------------------------
__global__ __launch_bounds__(256) void ln_k(const float* __restrict__ X,
                                            const float* __restrict__ W,
                                            const float* __restrict__ Bi,
                                            u16* __restrict__ Out) {
  const int row = blockIdx.x, tid = threadIdx.x;
  float4 x = *(const float4*)(X + (size_t)row * 1024 + tid * 4);
  float s = x.x + x.y + x.z + x.w;
  float s2 = x.x * x.x + x.y * x.y + x.z * x.z + x.w * x.w;
#pragma unroll
  for (int off = 32; off >= 1; off >>= 1) {
    s += __shfl_down(s, off);
    s2 += __shfl_down(s2, off);
  }
  __shared__ float red[8];
  int wave = tid >> 6, lane = tid & 63;
  if (lane == 0) { red[wave] = s; red[4 + wave] = s2; }
  __syncthreads();
  s = red[0] + red[1] + red[2] + red[3];
  s2 = red[4] + red[5] + red[6] + red[7];
  float mean = s * 0.0009765625f;
  float var = s2 * 0.0009765625f - mean * mean;
  float rs = rsqrtf(var + 1e-5f);
  float4 w = *(const float4*)(W + tid * 4);
  float4 b = *(const float4*)(Bi + tid * 4);
  u16* orow = Out + (size_t)row * 1024 + tid * 4;
  orow[0] = f2b((x.x - mean) * rs * w.x + b.x);
  orow[1] = f2b((x.y - mean) * rs * w.y + b.y);
  orow[2] = f2b((x.z - mean) * rs * w.z + b.z);
  orow[3] = f2b((x.w - mean) * rs * w.w + b.w);
}

// ---------------------------------------------------------------------------
// GEMM (m97 recipe): C[M,N] = A[M,K] @ Bt[N,K], bf16, 128x128 tile, BK=64,
// unpadded LDS + global_load_lds dwordx4 staging.
// EPI: 0 = fake-quant -> int-in-bf16;  1 = +bias +fp32 residual -> fp32
// ---------------------------------------------------------------------------
template <int EPI>
__global__ __launch_bounds__(256, 2) void gemm_bt(
    const u16* __restrict__ A, int lda, const u16* __restrict__ Bt, int ldb,
    void* __restrict__ Cp, int ldc, const float* __restrict__ bias,
    const float* __restrict__ res, int ldr, const float* __restrict__ dp,
    int M, int N, int K) {
  __shared__ __align__(16) u16 As[128 * 64];
  __shared__ __align__(16) u16 Bs[128 * 64];
  const int tid = threadIdx.x;
  const int lane = tid & 63, wave = tid >> 6;
  const int qd = lane >> 4, cl = lane & 15;
  const int wm = (wave & 1) << 6, wn = (wave >> 1) << 6;
  const int m0 = blockIdx.x * 128, n0 = blockIdx.y * 128;

  f32x4 acc[4][4];
  const f32x4 zero = {0.f, 0.f, 0.f, 0.f};
#pragma unroll
  for (int i = 0; i < 4; i++)
#pragma unroll
    for (int j = 0; j < 4; j++) acc[i][j] = zero;

  for (int k0 = 0; k0 < K; k0 += 64) {
    __syncthreads();
#pragma unroll
    for (int it = 0; it < 4; ++it) {
      int ch = it * 256 + tid;
      int r = ch >> 3, cc = (ch & 7) << 3;
      int gr = m0 + r;
      gr = gr < M ? gr : M - 1;
      glds16(A + (size_t)gr * lda + k0 + cc, As + ch * 8);
      glds16(Bt + (size_t)(n0 + r) * ldb + k0 + cc, Bs + ch * 8);
    }
    __syncthreads();
#pragma unroll
    for (int ks = 0; ks < 64; ks += 32) {
      short8 af[4], bf[4];
#pragma unroll
      for (int t = 0; t < 4; t++)
        af[t] = *(const short8*)(As + (wm + t * 16 + cl) * 64 + ks + qd * 8);
#pragma unroll
      for (int t = 0; t < 4; t++)
        bf[t] = *(const short8*)(Bs + (wn + t * 16 + cl) * 64 + ks + qd * 8);
#pragma unroll
      for (int mt = 0; mt < 4; mt++)
#pragma unroll
        for (int nt = 0; nt < 4; nt++)
          acc[mt][nt] = __builtin_amdgcn_mfma_f32_16x16x32_bf16(
              af[mt], bf[nt], acc[mt][nt], 0, 0, 0);
    }
  }

  float dscale = 1.f;
  if constexpr (EPI == 0) dscale = 1.0f / dp[0];
#pragma unroll
  for (int mt = 0; mt < 4; ++mt) {
#pragma unroll
    for (int r = 0; r < 4; ++r) {
      int row = m0 + wm + mt * 16 + qd * 4 + r;
      if (row >= M) continue;
#pragma unroll
      for (int nt = 0; nt < 4; ++nt) {
        int col = n0 + wn + nt * 16 + cl;
        float v = acc[mt][nt][r];
        if constexpr (EPI == 0) {
          float xq = rintf(v * dscale) + 128.f;
          xq = fminf(fmaxf(xq, 0.f), 255.f);
          ((u16*)Cp)[(size_t)row * ldc + col] = f2b(xq - 128.f);
        } else {
          v += bias[col] + res[(size_t)row * ldr + col];
          ((float*)Cp)[(size_t)row * ldc + col] = v;
        }
      }
    }
  }
}

// ---------------------------------------------------------------------------
// Fused FF1 + GEGLU (m97 staging): gg = (A@W1a + b1a) * gelu(A@W1g + b1g)
// ---------------------------------------------------------------------------
__global__ __launch_bounds__(256, 2) void ff1_geglu_k(
    const u16* __restrict__ A, const u16* __restrict__ W1t,
    const float* __restrict__ b1, u16* __restrict__ gg, int M) {
  __shared__ __align__(16) u16 As[128 * 64];
  __shared__ __align__(16) u16 Ba[64 * 64];
  __shared__ __align__(16) u16 Bg[64 * 64];
  const int tid = threadIdx.x;
  const int lane = tid & 63, wave = tid >> 6;
  const int qd = lane >> 4, cl = lane & 15;
  const int wm = (wave & 1) << 6, wn = (wave >> 1) << 5;
  const int m0 = blockIdx.x * 128, n0 = blockIdx.y * 64;

  f32x4 aca[4][2], acg[4][2];
  const f32x4 zero = {0.f, 0.f, 0.f, 0.f};
#pragma unroll
  for (int i = 0; i < 4; i++)
#pragma unroll
    for (int j = 0; j < 2; j++) { aca[i][j] = zero; acg[i][j] = zero; }

  for (int k0 = 0; k0 < 1024; k0 += 64) {
    __syncthreads();
#pragma unroll
    for (int it = 0; it < 4; ++it) {
      int ch = it * 256 + tid;
      int r = ch >> 3, cc = (ch & 7) << 3;
      glds16(A + (size_t)(m0 + r) * 1024 + k0 + cc, As + ch * 8);
    }
#pragma unroll
    for (int it = 0; it < 2; ++it) {
      int ch = it * 256 + tid;
      int r = ch >> 3, cc = (ch & 7) << 3;
      glds16(W1t + (size_t)(n0 + r) * 1024 + k0 + cc, Ba + ch * 8);
      glds16(W1t + (size_t)(4096 + n0 + r) * 1024 + k0 + cc, Bg + ch * 8);
    }
    __syncthreads();
#pragma unroll
    for (int ks = 0; ks < 64; ks += 32) {
      short8 af[4], ba[2], bg[2];
#pragma unroll
      for (int t = 0; t < 4; t++)
        af[t] = *(const short8*)(As + (wm + t * 16 + cl) * 64 + ks + qd * 8);
#pragma unroll
      for (int t = 0; t < 2; t++) {
        ba[t] = *(const short8*)(Ba + (wn + t * 16 + cl) * 64 + ks + qd * 8);
        bg[t] = *(const short8*)(Bg + (wn + t * 16 + cl) * 64 + ks + qd * 8);
      }
#pragma unroll
      for (int mt = 0; mt < 4; mt++)
#pragma unroll
        for (int nt = 0; nt < 2; nt++) {
          aca[mt][nt] = __builtin_amdgcn_mfma_f32_16x16x32_bf16(
              af[mt], ba[nt], aca[mt][nt], 0, 0, 0);
          acg[mt][nt] = __builtin_amdgcn_mfma_f32_16x16x32_bf16(
              af[mt], bg[nt], acg[mt][nt], 0, 0, 0);
        }
    }
  }
#pragma unroll
  for (int mt = 0; mt < 4; ++mt)
#pragma unroll
    for (int r = 0; r < 4; ++r) {
      int row = m0 + wm + mt * 16 + qd * 4 + r;
#pragma unroll
      for (int nt = 0; nt < 2; ++nt) {
        int col = n0 + wn + nt * 16 + cl;
        float a = aca[mt][nt][r] + b1[col];
        float g = acg[mt][nt][r] + b1[4096 + col];
        float ge = 0.5f * g * (1.0f + erff(g * 0.70710678118654752f));
        gg[(size_t)row * 4096 + col] = f2b(a * ge);
      }
    }
}

// ---------------------------------------------------------------------------
// Two-pass quantized attention (R5). Q/K/V ints-in-bf16 (exact MFMA sums).
// Block = 64 q-rows of one (b,h); wave owns 16 q-rows. S^T form both passes:
//   S^T tile = K_tile . Q^T : A-frag = K rows (keys), B-frag = Q rows.
//   D lane (qd,cl): keys nt*16+qd*4+r, q-row = cl.
// Pass A: stats (m,l) per q-row cl — 2 shfl-xor pairs per tile.
// Pass B: recompute S^T, quantize P -> packed b64 into per-wave Ps
// (P[q][key] layout), read back as A-frag; V^T tile staged to LDS, PV MFMA.
// K and V^T tiles staged coalesced via global_load_lds (m97 pattern).
// ---------------------------------------------------------------------------
__global__ __launch_bounds__(256, 4) void attn_k(
    const u16* __restrict__ Q, const u16* __restrict__ Kb,
    const u16* __restrict__ VbT, u16* __restrict__ O,
    const float* dqp, const float* dkp, const float* dvp, const float* dwp,
    int NK, int NKP) {
  __shared__ __align__(16) u16 Ks[64 * 64];
  __shared__ __align__(16) u16 VTs[64 * 64];
  __shared__ __align__(16) u16 Ps[4][16 * 72];
  const int tid = threadIdx.x;
  const int lane = tid & 63, wave = tid >> 6;
  const int qd = lane >> 4, cl = lane & 15;
  const int b = blockIdx.z, h = blockIdx.y, qt = blockIdx.x;
  const float sscale = dqp[0] * dkp[0] * 0.125f;  // dq*dk*DH^-0.5
  const float oscale = dwp[0] * dvp[0];
  const float inv_dw = 1.0f / dwp[0];
  const f32x4 zero = {0.f, 0.f, 0.f, 0.f};

  // Q B-frag for wave's q-rows: b[j] = Q[q=cl][k=qd*8+j]
  const u16* qrow =
      Q + (size_t)(b * 1024 + qt * 64 + wave * 16 + cl) * 1024 + h * 64;
  short8 qf[2];
  qf[0] = *(const short8*)(qrow + qd * 8);
  qf[1] = *(const short8*)(qrow + 32 + qd * 8);

  const u16* kbase = Kb + (size_t)(b * NK) * 1024 + h * 64;
  const u16* vtbase = VbT + ((size_t)b * 1024 + h * 64) * NKP;
  const int r_st = tid >> 3, c_st = (tid & 7) << 3;  // staging row/col

  // -------- PASS A: row stats --------
  float m_s = -1e30f, l_s = 0.f;
  for (int j0 = 0; j0 < NK; j0 += 64) {
    __syncthreads();
#pragma unroll
    for (int it = 0; it < 2; ++it) {
      int r = it * 32 + r_st;
      int j = j0 + r;
      j = j < NK ? j : NK - 1;  // clamp; masked below
      glds16(kbase + (size_t)j * 1024 + c_st, Ks + (it * 256 + tid) * 8);
    }
    __syncthreads();
    const bool full = (j0 + 64 <= NK);
    float sc[16];
#pragma unroll
    for (int nt = 0; nt < 4; ++nt) {
      short8 kf0 = *(const short8*)(Ks + (nt * 16 + cl) * 64 + qd * 8);
      short8 kf1 = *(const short8*)(Ks + (nt * 16 + cl) * 64 + 32 + qd * 8);
      f32x4 st = zero;
      st = __builtin_amdgcn_mfma_f32_16x16x32_bf16(kf0, qf[0], st, 0, 0, 0);
      st = __builtin_amdgcn_mfma_f32_16x16x32_bf16(kf1, qf[1], st, 0, 0, 0);
#pragma unroll
      for (int r = 0; r < 4; ++r) {
        int key = j0 + nt * 16 + qd * 4 + r;
        sc[nt * 4 + r] = (full || key < NK) ? st[r] * sscale : -1e30f;
      }
    }
    float mx = sc[0];
#pragma unroll
    for (int i = 1; i < 16; ++i) mx = fmaxf(mx, sc[i]);
    mx = fmaxf(mx, __shfl_xor(mx, 16));
    mx = fmaxf(mx, __shfl_xor(mx, 32));
    float mn = fmaxf(m_s, mx);
    float ss = 0.f;
#pragma unroll
    for (int i = 0; i < 16; ++i) ss += __expf(sc[i] - mn);
    ss += __shfl_xor(ss, 16);
    ss += __shfl_xor(ss, 32);
    l_s = l_s * __expf(m_s - mn) + ss;
    m_s = mn;
  }
  const float m_q = m_s, il_q = 1.0f / l_s;  // stats for q-row cl (all qd)

  // -------- PASS B: quantize P, PV --------
  f32x4 oacc[4];
#pragma unroll
  for (int t = 0; t < 4; t++) oacc[t] = zero;

  for (int j0 = 0; j0 < NK; j0 += 64) {
    __syncthreads();
#pragma unroll
    for (int it = 0; it < 2; ++it) {
      int r = it * 32 + r_st;
      int j = j0 + r;
      j = j < NK ? j : NK - 1;
      glds16(kbase + (size_t)j * 1024 + c_st, Ks + (it * 256 + tid) * 8);
      glds16(vtbase + (size_t)r * NKP + j0 + c_st, VTs + (it * 256 + tid) * 8);
    }
    __syncthreads();
    const bool full = (j0 + 64 <= NK);
#pragma unroll
    for (int nt = 0; nt < 4; ++nt) {
      short8 kf0 = *(const short8*)(Ks + (nt * 16 + cl) * 64 + qd * 8);
      short8 kf1 = *(const short8*)(Ks + (nt * 16 + cl) * 64 + 32 + qd * 8);
      f32x4 st = zero;
      st = __builtin_amdgcn_mfma_f32_16x16x32_bf16(kf0, qf[0], st, 0, 0, 0);
      st = __builtin_amdgcn_mfma_f32_16x16x32_bf16(kf1, qf[1], st, 0, 0, 0);
      u16 pk[4];
#pragma unroll
      for (int r = 0; r < 4; ++r) {
        int key = j0 + nt * 16 + qd * 4 + r;
        float aw = 0.f;
        if (full || key < NK) {
          float attn = __expf(st[r] * sscale - m_q) * il_q;
          aw = fminf(fmaxf(rintf(attn * inv_dw), 0.f), 255.f);
        }
        pk[r] = f2b(aw);
      }
      // P[q=cl][keys nt*16+qd*4 .. +3] : one packed 8-byte store
      uint2 pv;
      pv.x = (unsigned)pk[0] | ((unsigned)pk[1] << 16);
      pv.y = (unsigned)pk[2] | ((unsigned)pk[3] << 16);
      *(uint2*)(&Ps[wave][cl * 72 + nt * 16 + qd * 4]) = pv;
    }
    // wave-local DS ordering: no barrier needed between Ps write and read
#pragma unroll
    for (int ks = 0; ks < 2; ++ks) {
      short8 pf = *(const short8*)(&Ps[wave][cl * 72 + ks * 32 + qd * 8]);
#pragma unroll
      for (int dt = 0; dt < 4; ++dt) {
        short8 vf =
            *(const short8*)(VTs + (dt * 16 + cl) * 64 + ks * 32 + qd * 8);
        oacc[dt] =
            __builtin_amdgcn_mfma_f32_16x16x32_bf16(pf, vf, oacc[dt], 0, 0, 0);
      }
    }
  }
#pragma unroll
  for (int dt = 0; dt < 4; ++dt)
#pragma unroll
    for (int r = 0; r < 4; r++) {
      size_t addr =
          (size_t)(b * 1024 + qt * 64 + wave * 16 + qd * 4 + r) * 1024 +
          h * 64 + dt * 16 + cl;
      O[addr] = f2b(oacc[dt][r] * oscale);
    }
}

// ---------------------------------------------------------------------------
extern "C" void kernel_launch(void* const* d_in, const int* in_sizes, int n_in,
                              void* d_out, int out_size, void* d_ws,
                              size_t ws_size, hipStream_t stream) {
  (void)in_sizes; (void)n_in; (void)out_size; (void)ws_size;
  const float* x    = (const float*)d_in[0];
  const float* ctx  = (const float*)d_in[1];
  const float* n1w  = (const float*)d_in[2];
  const float* n1b  = (const float*)d_in[3];
  const float* n2w  = (const float*)d_in[4];
  const float* n2b  = (const float*)d_in[5];
  const float* n3w  = (const float*)d_in[6];
  const float* n3b  = (const float*)d_in[7];
  const float* a1wq = (const float*)d_in[8];
  const float* a1wk = (const float*)d_in[9];
  const float* a1wv = (const float*)d_in[10];
  const float* a1wo = (const float*)d_in[11];
  const float* a1bo = (const float*)d_in[12];
  const float* a2wq = (const float*)d_in[13];
  const float* a2wk = (const float*)d_in[14];
  const float* a2wv = (const float*)d_in[15];
  const float* a2wo = (const float*)d_in[16];
  const float* a2bo = (const float*)d_in[17];
  const float* ffw1 = (const float*)d_in[18];
  const float* ffb1 = (const float*)d_in[19];
  const float* ffw2 = (const float*)d_in[20];
  const float* ffb2 = (const float*)d_in[21];
  const float* d1q = (const float*)d_in[22];
  const float* d1k = (const float*)d_in[23];
  const float* d1v = (const float*)d_in[24];
  const float* d1w = (const float*)d_in[25];
  const float* d2q = (const float*)d_in[26];
  const float* d2k = (const float*)d_in[27];
  const float* d2v = (const float*)d_in[28];
  const float* d2w = (const float*)d_in[29];

  char* ws = (char*)d_ws;
  const size_t MB = 1u << 20;
  u16* W    = (u16*)(ws + 0 * MB);
  u16* lnb  = (u16*)(ws + 16 * MB);
  u16* qb   = (u16*)(ws + 24 * MB);
  u16* kb   = (u16*)(ws + 32 * MB);
  u16* vb   = (u16*)(ws + 40 * MB);
  u16* vbT  = (u16*)(ws + 48 * MB);   // [4][1024][1024]
  u16* ao   = (u16*)(ws + 56 * MB);
  float* x1 = (float*)(ws + 64 * MB); // fp32 trunk (x2 in place) -> 80 MB
  u16* k2b  = (u16*)(ws + 32 * MB);   // cross (kb/vb dead)
  u16* v2b  = (u16*)(ws + 33 * MB);
  u16* vbTc = (u16*)(ws + 34 * MB);   // [4][1024][128]
  u16* ctxb = (u16*)(ws + 35 * MB);   // [308][768]
  u16* gg   = (u16*)(ws + 24 * MB);   // FF: [4096][4096] over qb..vbT

  u16* WT0 = W;
  u16* WT1 = (u16*)(ws + 2 * MB);
  u16* WT2 = (u16*)(ws + 4 * MB);
  u16* WT3 = (u16*)(ws + 6 * MB);

  dim3 T256(256);
  // ================= attn1 (self) =================
  transpose_k<<<dim3(32, 32), T256, 0, stream>>>(a1wq, WT0, 1024, 1024);
  transpose_k<<<dim3(32, 32), T256, 0, stream>>>(a1wk, WT1, 1024, 1024);
  transpose_k<<<dim3(32, 32), T256, 0, stream>>>(a1wv, WT2, 1024, 1024);
  transpose_k<<<dim3(32, 32), T256, 0, stream>>>(a1wo, WT3, 1024, 1024);
  ln_k<<<4096, T256, 0, stream>>>(x, n1w, n1b, lnb);
  gemm_bt<0><<<dim3(32, 8), T256, 0, stream>>>(lnb, 1024, WT0, 1024, qb, 1024,
                                               nullptr, nullptr, 0, d1q, 4096,
                                               1024, 1024);
  gemm_bt<0><<<dim3(32, 8), T256, 0, stream>>>(lnb, 1024, WT1, 1024, kb, 1024,
                                               nullptr, nullptr, 0, d1k, 4096,
                                               1024, 1024);
  gemm_bt<0><<<dim3(32, 8), T256, 0, stream>>>(lnb, 1024, WT2, 1024, vb, 1024,
                                               nullptr, nullptr, 0, d1v, 4096,
                                               1024, 1024);
  tr16_k<<<dim3(32, 32, 4), T256, 0, stream>>>(vb, vbT, 1024, 1024);
  attn_k<<<dim3(16, 16, 4), T256, 0, stream>>>(qb, kb, vbT, ao, d1q, d1k, d1v,
                                               d1w, 1024, 1024);
  gemm_bt<1><<<dim3(32, 8), T256, 0, stream>>>(ao, 1024, WT3, 1024, x1, 1024,
                                               a1bo, x, 1024, nullptr, 4096,
                                               1024, 1024);
  // ================= attn2 (cross, CTX_N=77) =================
  transpose_k<<<dim3(32, 32), T256, 0, stream>>>(a2wq, WT0, 1024, 1024);
  transpose_k<<<dim3(32, 32), T256, 0, stream>>>(a2wo, WT1, 1024, 1024);
  transpose_k<<<dim3(32, 24), T256, 0, stream>>>(a2wk, WT2, 768, 1024);
  transpose_k<<<dim3(32, 24), T256, 0, stream>>>(a2wv, WT3, 768, 1024);
  ln_k<<<4096, T256, 0, stream>>>(x1, n2w, n2b, lnb);
  cast_k<<<231, T256, 0, stream>>>(ctx, ctxb);  // 308*768 = 231*1024
  gemm_bt<0><<<dim3(32, 8), T256, 0, stream>>>(lnb, 1024, WT0, 1024, qb, 1024,
                                               nullptr, nullptr, 0, d2q, 4096,
                                               1024, 1024);
  gemm_bt<0><<<dim3(3, 8), T256, 0, stream>>>(ctxb, 768, WT2, 768, k2b, 1024,
                                              nullptr, nullptr, 0, d2k, 308,
                                              1024, 768);
  gemm_bt<0><<<dim3(3, 8), T256, 0, stream>>>(ctxb, 768, WT3, 768, v2b, 1024,
                                              nullptr, nullptr, 0, d2v, 308,
                                              1024, 768);
  tr16_k<<<dim3(3, 32, 4), T256, 0, stream>>>(v2b, vbTc, 77, 128);
  attn_k<<<dim3(16, 16, 4), T256, 0, stream>>>(qb, k2b, vbTc, ao, d2q, d2k,
                                               d2v, d2w, 77, 128);
  gemm_bt<1><<<dim3(32, 8), T256, 0, stream>>>(ao, 1024, WT1, 1024, x1, 1024,
                                               a2bo, x1, 1024, nullptr, 4096,
                                               1024, 1024);  // x2 in place
  // ================= GEGLU FF =================
  transpose_k<<<dim3(256, 32), T256, 0, stream>>>(ffw1, W, 1024, 8192);
  ln_k<<<4096, T256, 0, stream>>>(x1, n3w, n3b, lnb);
  ff1_geglu_k<<<dim3(32, 64), T256, 0, stream>>>(lnb, W, ffb1, gg, 4096);
  transpose_k<<<dim3(32, 128), T256, 0, stream>>>(ffw2, W, 4096, 1024);
  gemm_bt<1><<<dim3(32, 8), T256, 0, stream>>>(gg, 4096, W, 4096, d_out, 1024,
                                               ffb2, x1, 1024, nullptr, 4096,
                                               1024, 4096);
}

// Round 7
// 588.593 us; speedup vs baseline: 1.3292x; 1.1435x over previous
//
#include <hip/hip_runtime.h>
#include <math.h>

// ---------------------------------------------------------------------------
// QuantBasicTransformerBlock on MI355X (gfx950). FP32 in/out, bf16 MFMA.
// B=4 N=1024 D=1024 H=16 DH=64 CTX_N=77 CTX_D=768 FF_HID=4096
//
// R7 = R6 with the cross-KV weight contiguity fix (WT3c = WT2 + 1024*768):
// fused QKV GEMM (N=3072), fused cross-KV GEMM (N=2048, contiguous panels),
// TM=64 GEMM variant (512 blocks) for N=1024 GEMMs, attention with 2
// q-groups/wave (halved staging), batched weight transposes.
// ---------------------------------------------------------------------------

typedef unsigned short u16;
typedef __attribute__((ext_vector_type(8))) short short8;   // 8 bf16 = 4 VGPR
typedef __attribute__((ext_vector_type(4))) float f32x4;

__device__ inline float b2f(u16 v) { return __uint_as_float(((unsigned)v) << 16); }
__device__ inline u16 f2b(float f) {             // round-to-nearest-even
  unsigned u = __float_as_uint(f);
  unsigned r = u + 0x7fffu + ((u >> 16) & 1u);
  return (u16)(r >> 16);
}

// async global->LDS, 16 B per lane (emits global_load_lds_dwordx4)
__device__ inline void glds16(const u16* g, u16* l) {
  __builtin_amdgcn_global_load_lds(
      (const __attribute__((address_space(1))) void*)g,
      (__attribute__((address_space(3))) void*)l, 16, 0, 0);
}

// ---------------------------------------------------------------------------
// Generic transpose fp32 in[R][C] -> bf16 out[C][R].
// ---------------------------------------------------------------------------
__global__ __launch_bounds__(256) void transpose_k(const float* __restrict__ in,
                                                   u16* __restrict__ out,
                                                   int R, int C) {
  __shared__ float t[32][33];
  int tx = threadIdx.x & 31, ty = threadIdx.x >> 5;  // 32 x 8
  int c0 = blockIdx.x * 32, r0 = blockIdx.y * 32;
#pragma unroll
  for (int i = 0; i < 32; i += 8)
    t[ty + i][tx] = in[(size_t)(r0 + ty + i) * C + c0 + tx];
  __syncthreads();
#pragma unroll
  for (int i = 0; i < 32; i += 8)
    out[(size_t)(c0 + ty + i) * R + r0 + tx] = f2b(t[tx][ty + i]);
}

// Batched variant: 4 weights (C=1024 each), z picks the weight. R may differ.
struct TrBatch { const float* in[4]; u16* out[4]; int R[4]; };
__global__ __launch_bounds__(256) void transpose4_k(TrBatch a) {
  int z = blockIdx.z;
  const float* in = a.in[z];
  u16* out = a.out[z];
  int R = a.R[z];
  int r0 = blockIdx.y * 32;
  if (r0 >= R) return;
  __shared__ float t[32][33];
  int tx = threadIdx.x & 31, ty = threadIdx.x >> 5;
  int c0 = blockIdx.x * 32;
#pragma unroll
  for (int i = 0; i < 32; i += 8)
    t[ty + i][tx] = in[(size_t)(r0 + ty + i) * 1024 + c0 + tx];
  __syncthreads();
#pragma unroll
  for (int i = 0; i < 32; i += 8)
    out[(size_t)(c0 + ty + i) * R + r0 + tx] = f2b(t[tx][ty + i]);
}

// ---------------------------------------------------------------------------
// Batched u16 transpose: in[b][n][1024] -> out[b][c][NKP], n clamped to NK.
// ---------------------------------------------------------------------------
__global__ __launch_bounds__(256) void tr16_k(const u16* __restrict__ in,
                                              u16* __restrict__ out, int NK,
                                              int NKP) {
  __shared__ u16 t[32][33];
  int tx = threadIdx.x & 31, ty = threadIdx.x >> 5;
  int n0 = blockIdx.x * 32, c0 = blockIdx.y * 32, b = blockIdx.z;
  const u16* ib = in + (size_t)b * NK * 1024;
  u16* ob = out + (size_t)b * 1024 * NKP;
#pragma unroll
  for (int i = 0; i < 32; i += 8) {
    int n = n0 + ty + i;
    n = n < NK ? n : NK - 1;
    t[ty + i][tx] = ib[(size_t)n * 1024 + c0 + tx];
  }
  __syncthreads();
#pragma unroll
  for (int i = 0; i < 32; i += 8)
    ob[(size_t)(c0 + ty + i) * NKP + n0 + tx] = t[tx][ty + i];
}

// ---------------------------------------------------------------------------
// fp32 -> bf16 cast, 4 elem/thread (n divisible by 1024).
// ---------------------------------------------------------------------------
__global__ __launch_bounds__(256) void cast_k(const float* __restrict__ in,
                                              u16* __restrict__ out) {
  int i = (blockIdx.x * 256 + threadIdx.x) * 4;
  float4 v = *(const float4*)(in + i);
  out[i + 0] = f2b(v.x);
  out[i + 1] = f2b(v.y);
  out[i + 2] = f2b(v.z);
  out[i + 3] = f2b(v.w);
}

// ---------------------------------------------------------------------------
// LayerNorm over D=1024 (fp32 in, bf16 out). One block per row.
// ---------------------------------------------------------------------------
__global__ __launch_bounds__(256) void ln_k(const float* __restrict__ X,
                                            const float* __restrict__ W,
                                            const float* __restrict__ Bi,
                                            u16* __restrict__ Out) {
  const int row = blockIdx.x, tid = threadIdx.x;
  float4 x = *(const float4*)(X + (size_t)row * 1024 + tid * 4);
  float s = x.x + x.y + x.z + x.w;
  float s2 = x.x * x.x + x.y * x.y + x.z * x.z + x.w * x.w;
#pragma unroll
  for (int off = 32; off >= 1; off >>= 1) {
    s += __shfl_down(s, off);
    s2 += __shfl_down(s2, off);
  }
  __shared__ float red[8];
  int wave = tid >> 6, lane = tid & 63;
  if (lane == 0) { red[wave] = s; red[4 + wave] = s2; }
  __syncthreads();
  s = red[0] + red[1] + red[2] + red[3];
  s2 = red[4] + red[5] + red[6] + red[7];
  float mean = s * 0.0009765625f;
  float var = s2 * 0.0009765625f - mean * mean;
  float rs = rsqrtf(var + 1e-5f);
  float4 w = *(const float4*)(W + tid * 4);
  float4 b = *(const float4*)(Bi + tid * 4);
  u16* orow = Out + (size_t)row * 1024 + tid * 4;
  orow[0] = f2b((x.x - mean) * rs * w.x + b.x);
  orow[1] = f2b((x.y - mean) * rs * w.y + b.y);
  orow[2] = f2b((x.z - mean) * rs * w.z + b.z);
  orow[3] = f2b((x.w - mean) * rs * w.w + b.w);
}

// ---------------------------------------------------------------------------
// GEMM (m97 recipe): C[M,N] = A[M,K] @ Bt[N,K], bf16, TMx128 tile, BK=64.
// EPI: 0 = fake-quant (single scale dp) -> int-in-bf16
//      1 = +bias +fp32 residual -> fp32
//      2 = fake-quant, multi-segment: seg = n0>>10 picks scale {dp,dp2,dp3}
//          and output base (u16*)Cp + seg*segsz; col within seg = col&1023.
// ---------------------------------------------------------------------------
template <int EPI, int TM>
__global__ __launch_bounds__(256, 2) void gemm_bt(
    const u16* __restrict__ A, int lda, const u16* __restrict__ Bt, int ldb,
    void* __restrict__ Cp, int ldc, const float* __restrict__ bias,
    const float* __restrict__ res, int ldr, const float* __restrict__ dp,
    const float* __restrict__ dp2, const float* __restrict__ dp3,
    size_t segsz, int M, int N, int K) {
  __shared__ __align__(16) u16 As[TM * 64];
  __shared__ __align__(16) u16 Bs[128 * 64];
  const int tid = threadIdx.x;
  const int lane = tid & 63, wave = tid >> 6;
  const int qd = lane >> 4, cl = lane & 15;
  const int wm = (wave & 1) * (TM / 2), wn = (wave >> 1) << 6;
  const int m0 = blockIdx.x * TM, n0 = blockIdx.y * 128;

  f32x4 acc[TM / 32][4];
  const f32x4 zero = {0.f, 0.f, 0.f, 0.f};
#pragma unroll
  for (int i = 0; i < TM / 32; i++)
#pragma unroll
    for (int j = 0; j < 4; j++) acc[i][j] = zero;

  for (int k0 = 0; k0 < K; k0 += 64) {
    __syncthreads();
#pragma unroll
    for (int it = 0; it < TM / 32; ++it) {
      int ch = it * 256 + tid;
      int r = ch >> 3, cc = (ch & 7) << 3;
      int gr = m0 + r;
      gr = gr < M ? gr : M - 1;
      glds16(A + (size_t)gr * lda + k0 + cc, As + ch * 8);
    }
#pragma unroll
    for (int it = 0; it < 4; ++it) {
      int ch = it * 256 + tid;
      int r = ch >> 3, cc = (ch & 7) << 3;
      glds16(Bt + (size_t)(n0 + r) * ldb + k0 + cc, Bs + ch * 8);
    }
    __syncthreads();
#pragma unroll
    for (int ks = 0; ks < 64; ks += 32) {
      short8 af[TM / 32], bf[4];
#pragma unroll
      for (int t = 0; t < TM / 32; t++)
        af[t] = *(const short8*)(As + (wm + t * 16 + cl) * 64 + ks + qd * 8);
#pragma unroll
      for (int t = 0; t < 4; t++)
        bf[t] = *(const short8*)(Bs + (wn + t * 16 + cl) * 64 + ks + qd * 8);
#pragma unroll
      for (int mt = 0; mt < TM / 32; mt++)
#pragma unroll
        for (int nt = 0; nt < 4; nt++)
          acc[mt][nt] = __builtin_amdgcn_mfma_f32_16x16x32_bf16(
              af[mt], bf[nt], acc[mt][nt], 0, 0, 0);
    }
  }

  float dscale = 1.f;
  u16* qbase = (u16*)Cp;
  if constexpr (EPI == 0) dscale = 1.0f / dp[0];
  if constexpr (EPI == 2) {
    int seg = n0 >> 10;
    const float* ds = (seg == 0) ? dp : ((seg == 1) ? dp2 : dp3);
    dscale = 1.0f / ds[0];
    qbase = (u16*)Cp + (size_t)seg * segsz;
  }
#pragma unroll
  for (int mt = 0; mt < TM / 32; ++mt) {
#pragma unroll
    for (int r = 0; r < 4; ++r) {
      int row = m0 + wm + mt * 16 + qd * 4 + r;
      if (row >= M) continue;
#pragma unroll
      for (int nt = 0; nt < 4; ++nt) {
        int col = n0 + wn + nt * 16 + cl;
        float v = acc[mt][nt][r];
        if constexpr (EPI == 0) {
          float xq = rintf(v * dscale) + 128.f;
          xq = fminf(fmaxf(xq, 0.f), 255.f);
          qbase[(size_t)row * ldc + col] = f2b(xq - 128.f);
        } else if constexpr (EPI == 2) {
          float xq = rintf(v * dscale) + 128.f;
          xq = fminf(fmaxf(xq, 0.f), 255.f);
          qbase[(size_t)row * ldc + (col & 1023)] = f2b(xq - 128.f);
        } else {
          v += bias[col] + res[(size_t)row * ldr + col];
          ((float*)Cp)[(size_t)row * ldc + col] = v;
        }
      }
    }
  }
}

// ---------------------------------------------------------------------------
// Fused FF1 + GEGLU: gg = (A@W1a + b1a) * gelu(A@W1g + b1g). 128x64 tile.
// ---------------------------------------------------------------------------
__global__ __launch_bounds__(256, 2) void ff1_geglu_k(
    const u16* __restrict__ A, const u16* __restrict__ W1t,
    const float* __restrict__ b1, u16* __restrict__ gg, int M) {
  __shared__ __align__(16) u16 As[128 * 64];
  __shared__ __align__(16) u16 Ba[64 * 64];
  __shared__ __align__(16) u16 Bg[64 * 64];
  const int tid = threadIdx.x;
  const int lane = tid & 63, wave = tid >> 6;
  const int qd = lane >> 4, cl = lane & 15;
  const int wm = (wave & 1) << 6, wn = (wave >> 1) << 5;
  const int m0 = blockIdx.x * 128, n0 = blockIdx.y * 64;

  f32x4 aca[4][2], acg[4][2];
  const f32x4 zero = {0.f, 0.f, 0.f, 0.f};
#pragma unroll
  for (int i = 0; i < 4; i++)
#pragma unroll
    for (int j = 0; j < 2; j++) { aca[i][j] = zero; acg[i][j] = zero; }

  for (int k0 = 0; k0 < 1024; k0 += 64) {
    __syncthreads();
#pragma unroll
    for (int it = 0; it < 4; ++it) {
      int ch = it * 256 + tid;
      int r = ch >> 3, cc = (ch & 7) << 3;
      glds16(A + (size_t)(m0 + r) * 1024 + k0 + cc, As + ch * 8);
    }
#pragma unroll
    for (int it = 0; it < 2; ++it) {
      int ch = it * 256 + tid;
      int r = ch >> 3, cc = (ch & 7) << 3;
      glds16(W1t + (size_t)(n0 + r) * 1024 + k0 + cc, Ba + ch * 8);
      glds16(W1t + (size_t)(4096 + n0 + r) * 1024 + k0 + cc, Bg + ch * 8);
    }
    __syncthreads();
#pragma unroll
    for (int ks = 0; ks < 64; ks += 32) {
      short8 af[4], ba[2], bg[2];
#pragma unroll
      for (int t = 0; t < 4; t++)
        af[t] = *(const short8*)(As + (wm + t * 16 + cl) * 64 + ks + qd * 8);
#pragma unroll
      for (int t = 0; t < 2; t++) {
        ba[t] = *(const short8*)(Ba + (wn + t * 16 + cl) * 64 + ks + qd * 8);
        bg[t] = *(const short8*)(Bg + (wn + t * 16 + cl) * 64 + ks + qd * 8);
      }
#pragma unroll
      for (int mt = 0; mt < 4; mt++)
#pragma unroll
        for (int nt = 0; nt < 2; nt++) {
          aca[mt][nt] = __builtin_amdgcn_mfma_f32_16x16x32_bf16(
              af[mt], ba[nt], aca[mt][nt], 0, 0, 0);
          acg[mt][nt] = __builtin_amdgcn_mfma_f32_16x16x32_bf16(
              af[mt], bg[nt], acg[mt][nt], 0, 0, 0);
        }
    }
  }
#pragma unroll
  for (int mt = 0; mt < 4; ++mt)
#pragma unroll
    for (int r = 0; r < 4; ++r) {
      int row = m0 + wm + mt * 16 + qd * 4 + r;
#pragma unroll
      for (int nt = 0; nt < 2; ++nt) {
        int col = n0 + wn + nt * 16 + cl;
        float a = aca[mt][nt][r] + b1[col];
        float g = acg[mt][nt][r] + b1[4096 + col];
        float ge = 0.5f * g * (1.0f + erff(g * 0.70710678118654752f));
        gg[(size_t)row * 4096 + col] = f2b(a * ge);
      }
    }
}

// ---------------------------------------------------------------------------
// Two-pass quantized attention: 2 q-groups per wave. Block = 128 q-rows of
// one (b,h); wave owns 16 q-rows per group (groups 64 rows apart). S^T form
// both passes (lane owns q-row cl). Each staged K/V^T tile feeds both groups.
// ---------------------------------------------------------------------------
__global__ __launch_bounds__(256, 4) void attn_k(
    const u16* __restrict__ Q, const u16* __restrict__ Kb,
    const u16* __restrict__ VbT, u16* __restrict__ O,
    const float* dqp, const float* dkp, const float* dvp, const float* dwp,
    int NK, int NKP) {
  __shared__ __align__(16) u16 Ks[64 * 64];
  __shared__ __align__(16) u16 VTs[64 * 64];
  __shared__ __align__(16) u16 Ps[4][16 * 72];
  const int tid = threadIdx.x;
  const int lane = tid & 63, wave = tid >> 6;
  const int qd = lane >> 4, cl = lane & 15;
  const int b = blockIdx.z, h = blockIdx.y, qt = blockIdx.x;
  const float sscale = dqp[0] * dkp[0] * 0.125f;  // dq*dk*DH^-0.5
  const float oscale = dwp[0] * dvp[0];
  const float inv_dw = 1.0f / dwp[0];
  const f32x4 zero = {0.f, 0.f, 0.f, 0.f};

  // Q B-frags for two q-groups: rows qt*128 + g*64 + wave*16 + cl
  short8 qf[2][2];
#pragma unroll
  for (int g = 0; g < 2; ++g) {
    const u16* qrow =
        Q + (size_t)(b * 1024 + qt * 128 + g * 64 + wave * 16 + cl) * 1024 +
        h * 64;
    qf[g][0] = *(const short8*)(qrow + qd * 8);
    qf[g][1] = *(const short8*)(qrow + 32 + qd * 8);
  }

  const u16* kbase = Kb + (size_t)(b * NK) * 1024 + h * 64;
  const u16* vtbase = VbT + ((size_t)b * 1024 + h * 64) * NKP;
  const int r_st = tid >> 3, c_st = (tid & 7) << 3;

  // -------- PASS A: row stats --------
  float m_s[2] = {-1e30f, -1e30f}, l_s[2] = {0.f, 0.f};
  for (int j0 = 0; j0 < NK; j0 += 64) {
    __syncthreads();
#pragma unroll
    for (int it = 0; it < 2; ++it) {
      int r = it * 32 + r_st;
      int j = j0 + r;
      j = j < NK ? j : NK - 1;
      glds16(kbase + (size_t)j * 1024 + c_st, Ks + (it * 256 + tid) * 8);
    }
    __syncthreads();
    const bool full = (j0 + 64 <= NK);
#pragma unroll
    for (int g = 0; g < 2; ++g) {
      float sc[16];
#pragma unroll
      for (int nt = 0; nt < 4; ++nt) {
        short8 kf0 = *(const short8*)(Ks + (nt * 16 + cl) * 64 + qd * 8);
        short8 kf1 = *(const short8*)(Ks + (nt * 16 + cl) * 64 + 32 + qd * 8);
        f32x4 st = zero;
        st = __builtin_amdgcn_mfma_f32_16x16x32_bf16(kf0, qf[g][0], st, 0, 0, 0);
        st = __builtin_amdgcn_mfma_f32_16x16x32_bf16(kf1, qf[g][1], st, 0, 0, 0);
#pragma unroll
        for (int r = 0; r < 4; ++r) {
          int key = j0 + nt * 16 + qd * 4 + r;
          sc[nt * 4 + r] = (full || key < NK) ? st[r] * sscale : -1e30f;
        }
      }
      float mx = sc[0];
#pragma unroll
      for (int i = 1; i < 16; ++i) mx = fmaxf(mx, sc[i]);
      mx = fmaxf(mx, __shfl_xor(mx, 16));
      mx = fmaxf(mx, __shfl_xor(mx, 32));
      float mn = fmaxf(m_s[g], mx);
      float ss = 0.f;
#pragma unroll
      for (int i = 0; i < 16; ++i) ss += __expf(sc[i] - mn);
      ss += __shfl_xor(ss, 16);
      ss += __shfl_xor(ss, 32);
      l_s[g] = l_s[g] * __expf(m_s[g] - mn) + ss;
      m_s[g] = mn;
    }
  }
  float il_s[2] = {1.0f / l_s[0], 1.0f / l_s[1]};

  // -------- PASS B: quantize P, PV --------
  f32x4 oacc[2][4];
#pragma unroll
  for (int g = 0; g < 2; ++g)
#pragma unroll
    for (int t = 0; t < 4; t++) oacc[g][t] = zero;

  for (int j0 = 0; j0 < NK; j0 += 64) {
    __syncthreads();
#pragma unroll
    for (int it = 0; it < 2; ++it) {
      int r = it * 32 + r_st;
      int j = j0 + r;
      j = j < NK ? j : NK - 1;
      glds16(kbase + (size_t)j * 1024 + c_st, Ks + (it * 256 + tid) * 8);
      glds16(vtbase + (size_t)r * NKP + j0 + c_st, VTs + (it * 256 + tid) * 8);
    }
    __syncthreads();
    const bool full = (j0 + 64 <= NK);
#pragma unroll
    for (int g = 0; g < 2; ++g) {
#pragma unroll
      for (int nt = 0; nt < 4; ++nt) {
        short8 kf0 = *(const short8*)(Ks + (nt * 16 + cl) * 64 + qd * 8);
        short8 kf1 = *(const short8*)(Ks + (nt * 16 + cl) * 64 + 32 + qd * 8);
        f32x4 st = zero;
        st = __builtin_amdgcn_mfma_f32_16x16x32_bf16(kf0, qf[g][0], st, 0, 0, 0);
        st = __builtin_amdgcn_mfma_f32_16x16x32_bf16(kf1, qf[g][1], st, 0, 0, 0);
        u16 pk[4];
#pragma unroll
        for (int r = 0; r < 4; ++r) {
          int key = j0 + nt * 16 + qd * 4 + r;
          float aw = 0.f;
          if (full || key < NK) {
            float attn = __expf(st[r] * sscale - m_s[g]) * il_s[g];
            aw = fminf(fmaxf(rintf(attn * inv_dw), 0.f), 255.f);
          }
          pk[r] = f2b(aw);
        }
        uint2 pv;
        pv.x = (unsigned)pk[0] | ((unsigned)pk[1] << 16);
        pv.y = (unsigned)pk[2] | ((unsigned)pk[3] << 16);
        *(uint2*)(&Ps[wave][cl * 72 + nt * 16 + qd * 4]) = pv;
      }
      // per-wave DS ordering: write->read->overwrite is in program order
#pragma unroll
      for (int ks = 0; ks < 2; ++ks) {
        short8 pf = *(const short8*)(&Ps[wave][cl * 72 + ks * 32 + qd * 8]);
#pragma unroll
        for (int dt = 0; dt < 4; ++dt) {
          short8 vf =
              *(const short8*)(VTs + (dt * 16 + cl) * 64 + ks * 32 + qd * 8);
          oacc[g][dt] = __builtin_amdgcn_mfma_f32_16x16x32_bf16(
              pf, vf, oacc[g][dt], 0, 0, 0);
        }
      }
    }
  }
#pragma unroll
  for (int g = 0; g < 2; ++g)
#pragma unroll
    for (int dt = 0; dt < 4; ++dt)
#pragma unroll
      for (int r = 0; r < 4; r++) {
        size_t addr = (size_t)(b * 1024 + qt * 128 + g * 64 + wave * 16 +
                               qd * 4 + r) * 1024 +
                      h * 64 + dt * 16 + cl;
        O[addr] = f2b(oacc[g][dt][r] * oscale);
      }
}

// ---------------------------------------------------------------------------
extern "C" void kernel_launch(void* const* d_in, const int* in_sizes, int n_in,
                              void* d_out, int out_size, void* d_ws,
                              size_t ws_size, hipStream_t stream) {
  (void)in_sizes; (void)n_in; (void)out_size; (void)ws_size;
  const float* x    = (const float*)d_in[0];
  const float* ctx  = (const float*)d_in[1];
  const float* n1w  = (const float*)d_in[2];
  const float* n1b  = (const float*)d_in[3];
  const float* n2w  = (const float*)d_in[4];
  const float* n2b  = (const float*)d_in[5];
  const float* n3w  = (const float*)d_in[6];
  const float* n3b  = (const float*)d_in[7];
  const float* a1wq = (const float*)d_in[8];
  const float* a1wk = (const float*)d_in[9];
  const float* a1wv = (const float*)d_in[10];
  const float* a1wo = (const float*)d_in[11];
  const float* a1bo = (const float*)d_in[12];
  const float* a2wq = (const float*)d_in[13];
  const float* a2wk = (const float*)d_in[14];
  const float* a2wv = (const float*)d_in[15];
  const float* a2wo = (const float*)d_in[16];
  const float* a2bo = (const float*)d_in[17];
  const float* ffw1 = (const float*)d_in[18];
  const float* ffb1 = (const float*)d_in[19];
  const float* ffw2 = (const float*)d_in[20];
  const float* ffb2 = (const float*)d_in[21];
  const float* d1q = (const float*)d_in[22];
  const float* d1k = (const float*)d_in[23];
  const float* d1v = (const float*)d_in[24];
  const float* d1w = (const float*)d_in[25];
  const float* d2q = (const float*)d_in[26];
  const float* d2k = (const float*)d_in[27];
  const float* d2v = (const float*)d_in[28];
  const float* d2w = (const float*)d_in[29];

  char* ws = (char*)d_ws;
  const size_t MB = 1u << 20;
  u16* W    = (u16*)(ws + 0 * MB);
  u16* lnb  = (u16*)(ws + 16 * MB);
  u16* qb   = (u16*)(ws + 24 * MB);   // contiguous qb/kb/vb: seg stride 8MB
  u16* kb   = (u16*)(ws + 32 * MB);
  u16* vb   = (u16*)(ws + 40 * MB);
  u16* vbT  = (u16*)(ws + 48 * MB);   // [4][1024][1024]
  u16* ao   = (u16*)(ws + 56 * MB);
  float* x1 = (float*)(ws + 64 * MB); // fp32 trunk (x2 in place) -> 80 MB
  u16* k2b  = (u16*)(ws + 32 * MB);   // cross: [2][308][1024] contiguous
  u16* v2b  = k2b + 308 * 1024;
  u16* vbTc = (u16*)(ws + 34 * MB);   // [4][1024][128]
  u16* ctxb = (u16*)(ws + 35 * MB);   // [308][768]
  u16* gg   = (u16*)(ws + 24 * MB);   // FF: [4096][4096] over qb..vbT

  u16* WT0 = W;                        // [1024][1024] slots, 2 MB each
  u16* WT1 = (u16*)(ws + 2 * MB);
  u16* WT2 = (u16*)(ws + 4 * MB);
  u16* WT3 = (u16*)(ws + 6 * MB);
  u16* WT3c = WT2 + 1024 * 768;        // cross V^T: contiguous after WT2

  dim3 T256(256);
  // ================= attn1 (self) =================
  {
    TrBatch tb;
    tb.in[0] = a1wq; tb.out[0] = WT0; tb.R[0] = 1024;
    tb.in[1] = a1wk; tb.out[1] = WT1; tb.R[1] = 1024;
    tb.in[2] = a1wv; tb.out[2] = WT2; tb.R[2] = 1024;
    tb.in[3] = a1wo; tb.out[3] = WT3; tb.R[3] = 1024;
    transpose4_k<<<dim3(32, 32, 4), T256, 0, stream>>>(tb);
  }
  ln_k<<<4096, T256, 0, stream>>>(x, n1w, n1b, lnb);
  // fused QKV: Bt = WT0|WT1|WT2 contiguous [3072][1024]
  gemm_bt<2, 128><<<dim3(32, 24), T256, 0, stream>>>(
      lnb, 1024, WT0, 1024, qb, 1024, nullptr, nullptr, 0, d1q, d1k, d1v,
      (size_t)4096 * 1024, 4096, 3072, 1024);
  tr16_k<<<dim3(32, 32, 4), T256, 0, stream>>>(vb, vbT, 1024, 1024);
  attn_k<<<dim3(8, 16, 4), T256, 0, stream>>>(qb, kb, vbT, ao, d1q, d1k, d1v,
                                              d1w, 1024, 1024);
  gemm_bt<1, 64><<<dim3(64, 8), T256, 0, stream>>>(
      ao, 1024, WT3, 1024, x1, 1024, a1bo, x, 1024, nullptr, nullptr, nullptr,
      0, 4096, 1024, 1024);
  // ================= attn2 (cross, CTX_N=77) =================
  {
    TrBatch tb;
    tb.in[0] = a2wq; tb.out[0] = WT0; tb.R[0] = 1024;
    tb.in[1] = a2wo; tb.out[1] = WT1; tb.R[1] = 1024;
    tb.in[2] = a2wk; tb.out[2] = WT2;  tb.R[2] = 768;
    tb.in[3] = a2wv; tb.out[3] = WT3c; tb.R[3] = 768;  // contiguous after WT2
    transpose4_k<<<dim3(32, 32, 4), T256, 0, stream>>>(tb);
  }
  ln_k<<<4096, T256, 0, stream>>>(x1, n2w, n2b, lnb);
  cast_k<<<231, T256, 0, stream>>>(ctx, ctxb);  // 308*768 = 231*1024
  gemm_bt<0, 64><<<dim3(64, 8), T256, 0, stream>>>(
      lnb, 1024, WT0, 1024, qb, 1024, nullptr, nullptr, 0, d2q, nullptr,
      nullptr, 0, 4096, 1024, 1024);
  // fused cross K/V: Bt = WT2|WT3c contiguous [2048][768]
  gemm_bt<2, 64><<<dim3(5, 16), T256, 0, stream>>>(
      ctxb, 768, WT2, 768, k2b, 1024, nullptr, nullptr, 0, d2k, d2v, nullptr,
      (size_t)308 * 1024, 308, 2048, 768);
  tr16_k<<<dim3(3, 32, 4), T256, 0, stream>>>(v2b, vbTc, 77, 128);
  attn_k<<<dim3(8, 16, 4), T256, 0, stream>>>(qb, k2b, vbTc, ao, d2q, d2k, d2v,
                                              d2w, 77, 128);
  gemm_bt<1, 64><<<dim3(64, 8), T256, 0, stream>>>(
      ao, 1024, WT1, 1024, x1, 1024, a2bo, x1, 1024, nullptr, nullptr, nullptr,
      0, 4096, 1024, 1024);  // x2 in place
  // ================= GEGLU FF =================
  transpose_k<<<dim3(256, 32), T256, 0, stream>>>(ffw1, W, 1024, 8192);
  ln_k<<<4096, T256, 0, stream>>>(x1, n3w, n3b, lnb);
  ff1_geglu_k<<<dim3(32, 64), T256, 0, stream>>>(lnb, W, ffb1, gg, 4096);
  transpose_k<<<dim3(32, 128), T256, 0, stream>>>(ffw2, W, 4096, 1024);
  gemm_bt<1, 64><<<dim3(64, 8), T256, 0, stream>>>(
      gg, 4096, W, 4096, d_out, 1024, ffb2, x1, 1024, nullptr, nullptr,
      nullptr, 0, 4096, 1024, 4096);
}